// Round 7
// baseline (182.919 us; speedup 1.0000x reference)
//
#include <hip/hip_runtime.h>

#define BATCH 64
#define LLEN 65536
#define NW 2047
#define STATS 321
#define NCHUNK 32   // chunks per row; each chunk = 2048 elements, 64 windows

// ---- wave64 sum via DPP (6 VALU adds); returns total (lane-63 value) uniform ----
__device__ __forceinline__ float dppWaveSumBcast(float x) {
    float t;
    t = __int_as_float(__builtin_amdgcn_update_dpp(0, __float_as_int(x), 0x111, 0xf, 0xf, true));  x += t; // row_shr:1
    t = __int_as_float(__builtin_amdgcn_update_dpp(0, __float_as_int(x), 0x112, 0xf, 0xf, true));  x += t; // row_shr:2
    t = __int_as_float(__builtin_amdgcn_update_dpp(0, __float_as_int(x), 0x114, 0xf, 0xf, true));  x += t; // row_shr:4
    t = __int_as_float(__builtin_amdgcn_update_dpp(0, __float_as_int(x), 0x118, 0xf, 0xf, true));  x += t; // row_shr:8
    t = __int_as_float(__builtin_amdgcn_update_dpp(0, __float_as_int(x), 0x142, 0xa, 0xf, false)); x += t; // row_bcast:15
    t = __int_as_float(__builtin_amdgcn_update_dpp(0, __float_as_int(x), 0x143, 0xc, 0xf, false)); x += t; // row_bcast:31
    return __int_as_float(__builtin_amdgcn_readlane(__float_as_int(x), 63));
}

// ---- per-row barrier among 8 blocks (monotonic counter, replay-safe) ----
__device__ __forceinline__ void rowBarrier(int* ctr) {
    __syncthreads();
    if (threadIdx.x == 0) {
        __threadfence();                       // release: raw slice visible device-wide
        atomicAdd(ctr, 1);
        while (atomicAdd(ctr, 0) < 8) __builtin_amdgcn_s_sleep(2);
        __threadfence();                       // acquire: invalidate stale cache lines
    }
    __syncthreads();
}

// ---------------- fused front-end: per-chunk histogram + windowed entropy ----------------
// grid (NCHUNK, BATCH), 256 threads. Stages chunk (+64-int halo) in LDS once;
// histogram from staged registers; windows read LDS. Lane k of each wave owns
// CDF level k and counts windows with entropy <= level_k (no atomics/binning).
__global__ __launch_bounds__(256) void front_kernel(const int* __restrict__ x,
                                                    int* __restrict__ hpart,
                                                    int* __restrict__ cpart,
                                                    int* __restrict__ bar) {
    __shared__ __align__(16) int ls[2112];
    __shared__ int lh[256];
    __shared__ int lc[256];
    const int row = blockIdx.y;
    const int c = blockIdx.x;
    const int t = threadIdx.x;
    lh[t] = 0;
    if (c == 0 && t < 2) bar[t * 64 + row] = 0;  // zero mlp barrier counters (stream order)
    __syncthreads();

    // --- stage chunk + halo; histogram from registers ---
    const int base4 = (row * LLEN + c * 2048) >> 2;  // int4 index
    const int4* xv = (const int4*)x;
    const int4 a0 = xv[base4 + t];
    const int4 a1 = xv[base4 + 256 + t];
    ((int4*)ls)[t] = a0;
    ((int4*)ls)[256 + t] = a1;
    if (t < 16) {
        const int gi = min(base4 + 512 + t, (BATCH * LLEN) / 4 - 1);  // clamp: tail garbage is masked
        ((int4*)ls)[512 + t] = xv[gi];
    }
    atomicAdd(&lh[min(max(a0.x, 0), 255)], 1);
    atomicAdd(&lh[min(max(a0.y, 0), 255)], 1);
    atomicAdd(&lh[min(max(a0.z, 0), 255)], 1);
    atomicAdd(&lh[min(max(a0.w, 0), 255)], 1);
    atomicAdd(&lh[min(max(a1.x, 0), 255)], 1);
    atomicAdd(&lh[min(max(a1.y, 0), 255)], 1);
    atomicAdd(&lh[min(max(a1.z, 0), 255)], 1);
    atomicAdd(&lh[min(max(a1.w, 0), 255)], 1);
    __syncthreads();

    // --- 16 windows per wave; window reads are ds_read_b32 with imm offsets ---
    const int lane = t & 63;
    const int wave = t >> 6;
    // e <= lv  <=>  S >= (6 - lv)*64, where S = sum_lanes log2(c_lane)
    const float lv = (lane == 63) ? 8.0f : (float)lane * (8.0f / 63.0f);
    const float T = (6.0f - lv) * 64.0f;
    const int wbase = c * 64 + wave * 16;
    const int lbase = wave * 512 + lane;  // int index in ls
    int cnt = 0;
#pragma unroll
    for (int i = 0; i < 16; ++i) {
        const int v = min(max(ls[lbase + i * 32], 0), 255);
        unsigned long long m = ~0ull;
#pragma unroll
        for (int k = 0; k < 8; ++k) {
            const unsigned long long b = __ballot(v & (1 << k));
            m &= ((v >> k) & 1) ? b : ~b;
        }
        const float S = dppWaveSumBcast(__log2f((float)__popcll(m)));
        cnt += (int)((S >= T) && (wbase + i < NW));
    }
    lc[t] = cnt;
    __syncthreads();

    hpart[(row * NCHUNK + c) * 256 + t] = lh[t];
    if (t < 64)
        cpart[(row * NCHUNK + c) * 64 + t] = lc[t] + lc[64 + t] + lc[128 + t] + lc[192 + t];
}

// ---------------- fused MLP: feats -> L1 -> LN/ReLU -> L2 -> LN/ReLU -> L3 ----------------
// grid (8, BATCH), 256 threads. 512 blocks, all co-resident; per-row spin
// barriers between layers (8 participants). Block cx owns a col slice per layer.
__global__ __launch_bounds__(256) void mlp_kernel(
    const int* __restrict__ hpart, const int* __restrict__ cpart,
    const float* __restrict__ W1, const float* __restrict__ b1,
    const float* __restrict__ g1, const float* __restrict__ be1,
    const float* __restrict__ W2, const float* __restrict__ b2,
    const float* __restrict__ g2, const float* __restrict__ be2,
    const float* __restrict__ W3, const float* __restrict__ b3,
    float* __restrict__ raw1, float* __restrict__ raw2,
    int* __restrict__ bar, float* __restrict__ out) {
    __shared__ float sa[512];
    __shared__ float part[1024];
    __shared__ float red[8];
    const int row = blockIdx.y;
    const int cx = blockIdx.x;
    const int t = threadIdx.x;

    // ---- feats into sa[0..321) ----
    int h = 0;
    const int* hp = hpart + row * (NCHUNK * 256) + t;
#pragma unroll
    for (int ch = 0; ch < NCHUNK; ++ch) h += hp[ch * 256];
    const float p = (float)h * (1.0f / 65536.0f);
    sa[t] = p;
    const float term = -p * log2f(p + 1e-10f);  // p==0 -> 0, matches ref
    const float s = dppWaveSumBcast(term);
    if ((t & 63) == 0) red[t >> 6] = s;
    if (t < 64) {
        int cc = 0;
        const int* cp = cpart + row * (NCHUNK * 64) + t;
#pragma unroll
        for (int ch = 0; ch < NCHUNK; ++ch) cc += cp[ch * 64];
        sa[257 + t] = (float)cc * (1.0f / 2047.0f);
    }
    __syncthreads();
    if (t == 0) sa[256] = red[0] + red[1] + red[2] + red[3];  // global entropy
    __syncthreads();

    // ---- layer 1: cols [cx*64, cx*64+64), K split 16 ways ----
    {
        const int cl = (t & 15) * 4;
        const int col = cx * 64 + cl;
        const int kg = t >> 4;
        const int klo = kg * 21;
        const int khi = min(klo + 21, STATS);
        float4 acc = {0.f, 0.f, 0.f, 0.f};
        for (int k = klo; k < khi; ++k) {
            const float a = sa[k];
            const float4 w = *(const float4*)&W1[k * 512 + col];
            acc.x = fmaf(a, w.x, acc.x);
            acc.y = fmaf(a, w.y, acc.y);
            acc.z = fmaf(a, w.z, acc.z);
            acc.w = fmaf(a, w.w, acc.w);
        }
        *(float4*)&part[kg * 64 + cl] = acc;
    }
    __syncthreads();
    if (t < 64) {
        float o = b1[cx * 64 + t];
#pragma unroll
        for (int g = 0; g < 16; ++g) o += part[g * 64 + t];
        raw1[row * 512 + cx * 64 + t] = o;
    }

    rowBarrier(&bar[row]);

    // ---- layer 2: LN(raw1)+ReLU, cols [cx*64, +64), K split 16 ways (KI=32) ----
    {
        const float v1 = raw1[row * 512 + t];
        const float v2 = raw1[row * 512 + 256 + t];
        const float sm = dppWaveSumBcast(v1 + v2);
        const float q = dppWaveSumBcast(v1 * v1 + v2 * v2);
        if ((t & 63) == 0) { red[t >> 6] = sm; red[4 + (t >> 6)] = q; }
        __syncthreads();
        const float mu = (red[0] + red[1] + red[2] + red[3]) * (1.0f / 512.0f);
        const float var = (red[4] + red[5] + red[6] + red[7]) * (1.0f / 512.0f) - mu * mu;
        const float rs = rsqrtf(var + 1e-5f);
        sa[t] = fmaxf((v1 - mu) * rs * g1[t] + be1[t], 0.0f);
        sa[t + 256] = fmaxf((v2 - mu) * rs * g1[t + 256] + be1[t + 256], 0.0f);
        __syncthreads();
        const int cl = (t & 15) * 4;
        const int col = cx * 64 + cl;
        const int kg = t >> 4;
        float4 acc = {0.f, 0.f, 0.f, 0.f};
#pragma unroll
        for (int i = 0; i < 32; ++i) {
            const int k = kg * 32 + i;
            const float a = sa[k];
            const float4 w = *(const float4*)&W2[k * 512 + col];
            acc.x = fmaf(a, w.x, acc.x);
            acc.y = fmaf(a, w.y, acc.y);
            acc.z = fmaf(a, w.z, acc.z);
            acc.w = fmaf(a, w.w, acc.w);
        }
        *(float4*)&part[kg * 64 + cl] = acc;
        __syncthreads();
        if (t < 64) {
            float o = b2[cx * 64 + t];
#pragma unroll
            for (int g = 0; g < 16; ++g) o += part[g * 64 + t];
            raw2[row * 512 + cx * 64 + t] = o;
        }
    }

    rowBarrier(&bar[64 + row]);

    // ---- layer 3: LN(raw2)+ReLU, cols [cx*32, +32), K split 32 ways (KI=16) ----
    {
        const float v1 = raw2[row * 512 + t];
        const float v2 = raw2[row * 512 + 256 + t];
        const float sm = dppWaveSumBcast(v1 + v2);
        const float q = dppWaveSumBcast(v1 * v1 + v2 * v2);
        if ((t & 63) == 0) { red[t >> 6] = sm; red[4 + (t >> 6)] = q; }
        __syncthreads();
        const float mu = (red[0] + red[1] + red[2] + red[3]) * (1.0f / 512.0f);
        const float var = (red[4] + red[5] + red[6] + red[7]) * (1.0f / 512.0f) - mu * mu;
        const float rs = rsqrtf(var + 1e-5f);
        sa[t] = fmaxf((v1 - mu) * rs * g2[t] + be2[t], 0.0f);
        sa[t + 256] = fmaxf((v2 - mu) * rs * g2[t + 256] + be2[t + 256], 0.0f);
        __syncthreads();
        const int cl = (t & 7) * 4;
        const int col = cx * 32 + cl;
        const int kg = t >> 3;
        float4 acc = {0.f, 0.f, 0.f, 0.f};
#pragma unroll
        for (int i = 0; i < 16; ++i) {
            const int k = kg * 16 + i;
            const float a = sa[k];
            const float4 w = *(const float4*)&W3[k * 256 + col];
            acc.x = fmaf(a, w.x, acc.x);
            acc.y = fmaf(a, w.y, acc.y);
            acc.z = fmaf(a, w.z, acc.z);
            acc.w = fmaf(a, w.w, acc.w);
        }
        *(float4*)&part[kg * 32 + cl] = acc;
        __syncthreads();
        if (t < 32) {
            float o = b3[cx * 32 + t];
#pragma unroll
            for (int g = 0; g < 32; ++g) o += part[g * 32 + t];
            out[row * 256 + cx * 32 + t] = o;
        }
    }
}

extern "C" void kernel_launch(void* const* d_in, const int* in_sizes, int n_in,
                              void* d_out, int out_size, void* d_ws, size_t ws_size,
                              hipStream_t stream) {
    const int* x = (const int*)d_in[0];
    const float* W1 = (const float*)d_in[1];
    const float* b1 = (const float*)d_in[2];
    const float* g1 = (const float*)d_in[3];
    const float* be1 = (const float*)d_in[4];
    const float* W2 = (const float*)d_in[5];
    const float* b2 = (const float*)d_in[6];
    const float* g2 = (const float*)d_in[7];
    const float* be2 = (const float*)d_in[8];
    const float* W3 = (const float*)d_in[9];
    const float* b3 = (const float*)d_in[10];
    float* out = (float*)d_out;

    char* ws = (char*)d_ws;
    int* hpart = (int*)ws;                     // 64*32*256*4 = 2 MiB
    int* cpart = (int*)(ws + 2097152);         // 64*32*64*4  = 512 KiB
    float* raw1 = (float*)(ws + 2621440);      // 64*512*4 = 128 KiB
    float* raw2 = (float*)(ws + 2752512);      // 64*512*4 = 128 KiB
    int* bar = (int*)(ws + 2883584);           // 128 ints (zeroed by front_kernel)

    front_kernel<<<dim3(NCHUNK, BATCH), 256, 0, stream>>>(x, hpart, cpart, bar);
    mlp_kernel<<<dim3(8, BATCH), 256, 0, stream>>>(hpart, cpart, W1, b1, g1, be1,
                                                   W2, b2, g2, be2, W3, b3,
                                                   raw1, raw2, bar, out);
}

// Round 8
// 121.617 us; speedup vs baseline: 1.5041x; 1.5041x over previous
//
#include <hip/hip_runtime.h>

#define BATCH 64
#define LLEN 65536
#define NW 2047
#define STATS 321
#define NCHUNK 32   // chunks per row; each chunk = 2048 elements, 64 windows

// ---- wave64 sum via DPP (6 VALU adds); returns total (lane-63 value) uniform ----
__device__ __forceinline__ float dppWaveSumBcast(float x) {
    float t;
    t = __int_as_float(__builtin_amdgcn_update_dpp(0, __float_as_int(x), 0x111, 0xf, 0xf, true));  x += t; // row_shr:1
    t = __int_as_float(__builtin_amdgcn_update_dpp(0, __float_as_int(x), 0x112, 0xf, 0xf, true));  x += t; // row_shr:2
    t = __int_as_float(__builtin_amdgcn_update_dpp(0, __float_as_int(x), 0x114, 0xf, 0xf, true));  x += t; // row_shr:4
    t = __int_as_float(__builtin_amdgcn_update_dpp(0, __float_as_int(x), 0x118, 0xf, 0xf, true));  x += t; // row_shr:8
    t = __int_as_float(__builtin_amdgcn_update_dpp(0, __float_as_int(x), 0x142, 0xa, 0xf, false)); x += t; // row_bcast:15
    t = __int_as_float(__builtin_amdgcn_update_dpp(0, __float_as_int(x), 0x143, 0xc, 0xf, false)); x += t; // row_bcast:31
    return __int_as_float(__builtin_amdgcn_readlane(__float_as_int(x), 63));
}

// ---------------- fused front-end: per-chunk histogram + windowed entropy ----------------
// grid (NCHUNK, BATCH), 256 threads. Stages chunk (+64-int halo) in LDS once;
// histogram from staged registers; windows read LDS (ds_read_b32, imm offsets).
// Lane k of each wave owns CDF level k: counts windows with entropy <= level_k.
__global__ __launch_bounds__(256) void front_kernel(const int* __restrict__ x,
                                                    int* __restrict__ hpart,
                                                    int* __restrict__ cpart) {
    __shared__ __align__(16) int ls[2112];
    __shared__ int lh[256];
    __shared__ int lc[256];
    const int row = blockIdx.y;
    const int c = blockIdx.x;
    const int t = threadIdx.x;
    lh[t] = 0;
    __syncthreads();

    // --- stage chunk + halo; histogram from registers ---
    const int base4 = (row * LLEN + c * 2048) >> 2;  // int4 index
    const int4* xv = (const int4*)x;
    const int4 a0 = xv[base4 + t];
    const int4 a1 = xv[base4 + 256 + t];
    ((int4*)ls)[t] = a0;
    ((int4*)ls)[256 + t] = a1;
    if (t < 16) {
        const int gi = min(base4 + 512 + t, (BATCH * LLEN) / 4 - 1);  // clamp: tail garbage is masked
        ((int4*)ls)[512 + t] = xv[gi];
    }
    atomicAdd(&lh[min(max(a0.x, 0), 255)], 1);
    atomicAdd(&lh[min(max(a0.y, 0), 255)], 1);
    atomicAdd(&lh[min(max(a0.z, 0), 255)], 1);
    atomicAdd(&lh[min(max(a0.w, 0), 255)], 1);
    atomicAdd(&lh[min(max(a1.x, 0), 255)], 1);
    atomicAdd(&lh[min(max(a1.y, 0), 255)], 1);
    atomicAdd(&lh[min(max(a1.z, 0), 255)], 1);
    atomicAdd(&lh[min(max(a1.w, 0), 255)], 1);
    __syncthreads();

    // --- 16 windows per wave; e <= lv  <=>  S >= (6 - lv)*64, S = sum log2(c_lane) ---
    const int lane = t & 63;
    const int wave = t >> 6;
    const float lv = (lane == 63) ? 8.0f : (float)lane * (8.0f / 63.0f);
    const float T = (6.0f - lv) * 64.0f;
    const int wbase = c * 64 + wave * 16;
    const int lbase = wave * 512 + lane;  // int index in ls
    int cnt = 0;
#pragma unroll
    for (int i = 0; i < 16; ++i) {
        const int v = min(max(ls[lbase + i * 32], 0), 255);
        unsigned long long m = ~0ull;
#pragma unroll
        for (int k = 0; k < 8; ++k) {
            const unsigned long long b = __ballot(v & (1 << k));
            m &= ((v >> k) & 1) ? b : ~b;
        }
        const float S = dppWaveSumBcast(__log2f((float)__popcll(m)));
        cnt += (int)((S >= T) && (wbase + i < NW));
    }
    lc[t] = cnt;
    __syncthreads();

    hpart[(row * NCHUNK + c) * 256 + t] = lh[t];
    if (t < 64)
        cpart[(row * NCHUNK + c) * 64 + t] = lc[t] + lc[64 + t] + lc[128 + t] + lc[192 + t];
}

// ---------------- feats + MLP layer 1: [321] @ W1[321,512] + b1 -> raw1 ----------------
__global__ __launch_bounds__(256) void gemm1_kernel(
    const int* __restrict__ hpart, const int* __restrict__ cpart,
    const float* __restrict__ W, const float* __restrict__ b,
    float* __restrict__ out) {
    __shared__ float sa[STATS];
    __shared__ float red[4];
    __shared__ float part[16][64];
    const int row = blockIdx.y;
    const int t = threadIdx.x;

    // sum histogram partials over chunks
    int h = 0;
    const int* hp = hpart + row * (NCHUNK * 256) + t;
#pragma unroll
    for (int ch = 0; ch < NCHUNK; ++ch) h += hp[ch * 256];
    const float p = (float)h * (1.0f / 65536.0f);
    sa[t] = p;
    const float term = -p * log2f(p + 1e-10f);  // p==0 -> 0, matches ref
    const float s = dppWaveSumBcast(term);
    if ((t & 63) == 0) red[t >> 6] = s;

    // per-level CDF counts (already cumulative in meaning)
    if (t < 64) {
        int cc = 0;
        const int* cp = cpart + row * (NCHUNK * 64) + t;
#pragma unroll
        for (int ch = 0; ch < NCHUNK; ++ch) cc += cp[ch * 64];
        sa[257 + t] = (float)cc * (1.0f / 2047.0f);
    }
    __syncthreads();
    if (t == 0) sa[256] = red[0] + red[1] + red[2] + red[3];  // global entropy
    __syncthreads();

    const int cl = (t & 15) * 4;
    const int col = blockIdx.x * 64 + cl;
    const int kg = t >> 4;
    const int klo = kg * 21;
    const int khi = min(klo + 21, STATS);
    float4 acc = {0.f, 0.f, 0.f, 0.f};
    for (int k = klo; k < khi; ++k) {
        const float a = sa[k];
        const float4 w = *(const float4*)&W[k * 512 + col];
        acc.x = fmaf(a, w.x, acc.x);
        acc.y = fmaf(a, w.y, acc.y);
        acc.z = fmaf(a, w.z, acc.z);
        acc.w = fmaf(a, w.w, acc.w);
    }
    *(float4*)&part[kg][cl] = acc;
    __syncthreads();
    if (t < 64) {
        float o = b[blockIdx.x * 64 + t];
#pragma unroll
        for (int g = 0; g < 16; ++g) o += part[g][t];
        out[row * 512 + blockIdx.x * 64 + t] = o;
    }
}

// ---------------- MLP layers 2/3: LN(raw)+ReLU then @ W + b ----------------
template <int NOUT, int CPB>
__global__ __launch_bounds__(256) void gemm_ln_kernel(
    const float* __restrict__ raw, const float* __restrict__ g,
    const float* __restrict__ be, const float* __restrict__ W,
    const float* __restrict__ b, float* __restrict__ out) {
    constexpr int TC = CPB / 4;
    constexpr int KG = 256 / TC;
    constexpr int KI = 512 / KG;
    __shared__ float sa[512];
    __shared__ float red[8];
    __shared__ float part[KG][CPB];
    const int row = blockIdx.y;
    const int t = threadIdx.x;

    const float v1 = raw[row * 512 + t];
    const float v2 = raw[row * 512 + 256 + t];
    const float s = dppWaveSumBcast(v1 + v2);
    const float q = dppWaveSumBcast(v1 * v1 + v2 * v2);
    if ((t & 63) == 0) { red[t >> 6] = s; red[4 + (t >> 6)] = q; }
    __syncthreads();
    const float mu = (red[0] + red[1] + red[2] + red[3]) * (1.0f / 512.0f);
    const float var = (red[4] + red[5] + red[6] + red[7]) * (1.0f / 512.0f) - mu * mu;
    const float rs = rsqrtf(var + 1e-5f);
    sa[t] = fmaxf((v1 - mu) * rs * g[t] + be[t], 0.0f);
    sa[t + 256] = fmaxf((v2 - mu) * rs * g[t + 256] + be[t + 256], 0.0f);
    __syncthreads();

    const int cl = (t % TC) * 4;
    const int col = blockIdx.x * CPB + cl;
    const int kg = t / TC;
    float4 acc = {0.f, 0.f, 0.f, 0.f};
#pragma unroll
    for (int i = 0; i < KI; ++i) {
        const int k = kg * KI + i;
        const float a = sa[k];
        const float4 w = *(const float4*)&W[k * NOUT + col];
        acc.x = fmaf(a, w.x, acc.x);
        acc.y = fmaf(a, w.y, acc.y);
        acc.z = fmaf(a, w.z, acc.z);
        acc.w = fmaf(a, w.w, acc.w);
    }
    *(float4*)&part[kg][cl] = acc;
    __syncthreads();
    if (t < CPB) {
        float o = b[blockIdx.x * CPB + t];
#pragma unroll
        for (int gi = 0; gi < KG; ++gi) o += part[gi][t];
        out[row * NOUT + blockIdx.x * CPB + t] = o;
    }
}

extern "C" void kernel_launch(void* const* d_in, const int* in_sizes, int n_in,
                              void* d_out, int out_size, void* d_ws, size_t ws_size,
                              hipStream_t stream) {
    const int* x = (const int*)d_in[0];
    const float* W1 = (const float*)d_in[1];
    const float* b1 = (const float*)d_in[2];
    const float* g1 = (const float*)d_in[3];
    const float* be1 = (const float*)d_in[4];
    const float* W2 = (const float*)d_in[5];
    const float* b2 = (const float*)d_in[6];
    const float* g2 = (const float*)d_in[7];
    const float* be2 = (const float*)d_in[8];
    const float* W3 = (const float*)d_in[9];
    const float* b3 = (const float*)d_in[10];
    float* out = (float*)d_out;

    char* ws = (char*)d_ws;
    int* hpart = (int*)ws;                     // 64*32*256*4 = 2 MiB
    int* cpart = (int*)(ws + 2097152);         // 64*32*64*4  = 512 KiB
    float* raw1 = (float*)(ws + 2621440);      // 64*512*4 = 128 KiB
    float* raw2 = (float*)(ws + 2752512);      // 64*512*4 = 128 KiB

    front_kernel<<<dim3(NCHUNK, BATCH), 256, 0, stream>>>(x, hpart, cpart);
    gemm1_kernel<<<dim3(8, BATCH), 256, 0, stream>>>(hpart, cpart, W1, b1, raw1);
    gemm_ln_kernel<512, 64><<<dim3(8, BATCH), 256, 0, stream>>>(raw1, g1, be1, W2, b2, raw2);
    gemm_ln_kernel<256, 32><<<dim3(8, BATCH), 256, 0, stream>>>(raw2, g2, be2, W3, b3, out);
}